// Round 8
// baseline (860.097 us; speedup 1.0000x reference)
//
#include <hip/hip_runtime.h>
#include <hip/hip_bf16.h>

#define H_DIM 2048
#define E_NUM 8
#define I_DIM 4096
#define TWO_I 8192
#define T_TOK 2048

typedef __bf16 bf16x8 __attribute__((ext_vector_type(8)));
typedef float f32x4 __attribute__((ext_vector_type(4)));

static __device__ __forceinline__ unsigned short f2bs(float x) {
    __hip_bfloat16 h = __float2bfloat16(x);
    return __builtin_bit_cast(unsigned short, h);
}

#define MFMA16(a, b, c) __builtin_amdgcn_mfma_f32_16x16x32_bf16(a, b, c, 0, 0, 0)
#define BSWZ(n) (((((n) & 7) ^ (((n) >> 2) & 7))) << 4)
// barrier WITHOUT vmcnt drain: LDS ops visible, global loads stay in flight
#define BARRIER() asm volatile("s_waitcnt lgkmcnt(0)\ns_barrier" ::: "memory")

static __device__ __forceinline__ bf16x8 bload(
    const unsigned short* __restrict__ Bs, int n, int s, int h) {
    int off = (n * 128 + s * 64 + h * 16) ^ BSWZ(n);
    return *reinterpret_cast<const bf16x8*>((const char*)Bs + off);
}

// ---------------- fused router + convert: one wave per token ----------------
__global__ __launch_bounds__(256) void router_convert_kernel(
    const float* __restrict__ hs, const float* __restrict__ rw,
    float* __restrict__ out_scores, int* __restrict__ eidx,
    unsigned short* __restrict__ xb, unsigned short* __restrict__ xs) {
    int tok = blockIdx.x * 4 + (threadIdx.x >> 6);
    int lane = threadIdx.x & 63;
    const float* row = hs + (size_t)tok * H_DIM;
    float4 v[8];
    float acc[E_NUM];
#pragma unroll
    for (int e = 0; e < E_NUM; e++) acc[e] = 0.f;
#pragma unroll
    for (int i = 0; i < 8; i++) {
        int hb = i * 256 + lane * 4;
        v[i] = *reinterpret_cast<const float4*>(row + hb);
        const float* w0 = rw + (size_t)hb * E_NUM;
#pragma unroll
        for (int e = 0; e < E_NUM; e++) {
            acc[e] += v[i].x * w0[e] + v[i].y * w0[E_NUM + e] +
                      v[i].z * w0[2 * E_NUM + e] + v[i].w * w0[3 * E_NUM + e];
        }
    }
#pragma unroll
    for (int e = 0; e < E_NUM; e++) {
#pragma unroll
        for (int o = 32; o > 0; o >>= 1) acc[e] += __shfl_xor(acc[e], o, 64);
    }
    int best = 0; float bv = acc[0];
#pragma unroll
    for (int e = 1; e < E_NUM; e++) { if (acc[e] > bv) { bv = acc[e]; best = e; } }
    float sc = 1.f / (1.f + expf(-bv));
    if (lane < E_NUM) out_scores[(size_t)lane * T_TOK + tok] = (lane == best) ? sc : 0.f;
    if (lane == 0) eidx[tok] = best;
    unsigned short* xbr = xb + (size_t)tok * H_DIM;
    unsigned short* xsr = xs + (size_t)tok * H_DIM;
#pragma unroll
    for (int i = 0; i < 8; i++) {
        int hb = i * 256 + lane * 4;
        ushort4 b, s4;
        b.x = f2bs(v[i].x); b.y = f2bs(v[i].y); b.z = f2bs(v[i].z); b.w = f2bs(v[i].w);
        s4.x = f2bs(v[i].x * sc); s4.y = f2bs(v[i].y * sc);
        s4.z = f2bs(v[i].z * sc); s4.w = f2bs(v[i].w * sc);
        *reinterpret_cast<ushort4*>(xbr + hb) = b;
        *reinterpret_cast<ushort4*>(xsr + hb) = s4;
    }
}

// ---------------- grouping ----------------
__global__ void group_kernel(const int* __restrict__ eidx, int* __restrict__ perm,
                             int* __restrict__ off) {
    __shared__ int cnt[E_NUM];
    __shared__ int base[E_NUM];
    int t = threadIdx.x;
    if (t < E_NUM) cnt[t] = 0;
    __syncthreads();
    for (int i = t; i < T_TOK; i += 256) atomicAdd(&cnt[eidx[i]], 1);
    __syncthreads();
    if (t == 0) {
        int s = 0;
        for (int e = 0; e < E_NUM; e++) { base[e] = s; off[e] = s; s += cnt[e]; }
        off[E_NUM] = s;
    }
    __syncthreads();
    for (int i = t; i < T_TOK; i += 256) {
        int e = eidx[i];
        int p = atomicAdd(&base[e], 1);
        perm[p] = i;
    }
}

// ---------------- GEMM1: gate_up streaming, single-barrier dbuf, 2-deep B prefetch
// 256 thr = 4 m-waves x 64 rows (BM=256). 32 gate + 32 up cols. BK=64.
// grid.x = I/32 (128), grid.y = g*8 + mt
__global__ __launch_bounds__(256, 3) void gemm1_kernel(
    const unsigned short* __restrict__ xb, const unsigned short* __restrict__ xs,
    const float* __restrict__ gup, const float* __restrict__ sg,
    const float* __restrict__ su, const int* __restrict__ perm,
    const int* __restrict__ off, unsigned short* __restrict__ hmid) {
    int nt = blockIdx.x;
    int g = blockIdx.y >> 3;
    int mt = blockIdx.y & 7;
    int rowbase, ng;
    if (g < E_NUM) { rowbase = off[g]; ng = off[g + 1] - rowbase; }
    else { rowbase = 0; ng = T_TOK; }
    int mstart = mt * 256;
    if (mstart >= ng) return;

    __shared__ unsigned short Bg[2][32 * 64];   // 2 x 4 KB
    __shared__ unsigned short Bu[2][32 * 64];   // 2 x 4 KB

    int tid = threadIdx.x;
    int wave = tid >> 6, lane = tid & 63;
    int ln = lane & 15, h = lane >> 4;

    const unsigned short* Abase = (g == E_NUM) ? xb : xs;
    const unsigned short* Ap0; const unsigned short* Ap1;
    const unsigned short* Ap2; const unsigned short* Ap3;
#define MKAP(i, dst) { int r_ = mstart + wave * 64 + i * 16 + ln; \
        r_ = (r_ < ng) ? r_ : (ng - 1); \
        int tok_ = (g < E_NUM) ? perm[rowbase + r_] : r_; \
        dst = Abase + (size_t)tok_ * H_DIM + h * 8; }
    MKAP(0, Ap0) MKAP(1, Ap1) MKAP(2, Ap2) MKAP(3, Ap3)
#undef MKAP

    const float* gbase; const float* ubase; size_t ldb;
    if (g < E_NUM) {
        gbase = gup + (size_t)g * H_DIM * TWO_I + nt * 32;
        ubase = gbase + I_DIM;
        ldb = TWO_I;
    } else {
        gbase = sg + nt * 32;
        ubase = su + nt * 32;
        ldb = I_DIM;
    }
    int nb = (tid & 7) * 4;          // 4 n-cols
    int kk = (tid >> 3) * 2;         // 2 k-rows
    const float* pg = gbase + (size_t)kk * ldb + nb;
    const float* pu = ubase + (size_t)kk * ldb + nb;

    f32x4 zero = {0.f, 0.f, 0.f, 0.f};
    f32x4 accg[4][2], accu[4][2];
#pragma unroll
    for (int i = 0; i < 4; i++)
#pragma unroll
        for (int j = 0; j < 2; j++) { accg[i][j] = zero; accu[i][j] = zero; }

    const int NT = H_DIM / 64;   // 32, even
    f32x4 gA0, gA1, uA0, uA1;    // q-set A
    f32x4 gB0, gB1, uB0, uB1;    // q-set B
    bf16x8 aA0, aA1, aA2, aA3, aB0, aB1, aB2, aB3;

#define G1_LOADQ(q0_, q1_, r0_, r1_, t_) { size_t ko_ = (size_t)(t_) * 64 * ldb; \
        q0_ = *reinterpret_cast<const f32x4*>(pg + ko_); \
        q1_ = *reinterpret_cast<const f32x4*>(pg + ko_ + ldb); \
        r0_ = *reinterpret_cast<const f32x4*>(pu + ko_); \
        r1_ = *reinterpret_cast<const f32x4*>(pu + ko_ + ldb); }
#define G1_WRITEQ(q0_, q1_, r0_, r1_, buf_) { _Pragma("unroll") \
        for (int i_ = 0; i_ < 4; i_++) { int n_ = nb + i_; \
            unsigned og_ = (unsigned)f2bs(q0_[i_]) | ((unsigned)f2bs(q1_[i_]) << 16); \
            unsigned ou_ = (unsigned)f2bs(r0_[i_]) | ((unsigned)f2bs(r1_[i_]) << 16); \
            int ob_ = (n_ * 128 + kk * 2) ^ BSWZ(n_); \
            *reinterpret_cast<unsigned*>((char*)Bg[buf_] + ob_) = og_; \
            *reinterpret_cast<unsigned*>((char*)Bu[buf_] + ob_) = ou_; } }
#define G1_COMPUTE(rb_, s_, x0_, x1_, x2_, x3_) { \
        bf16x8 bg0_ = bload(Bg[rb_], ln, s_, h), bg1_ = bload(Bg[rb_], 16 + ln, s_, h); \
        bf16x8 bu0_ = bload(Bu[rb_], ln, s_, h), bu1_ = bload(Bu[rb_], 16 + ln, s_, h); \
        accg[0][0] = MFMA16(x0_, bg0_, accg[0][0]); accg[0][1] = MFMA16(x0_, bg1_, accg[0][1]); \
        accu[0][0] = MFMA16(x0_, bu0_, accu[0][0]); accu[0][1] = MFMA16(x0_, bu1_, accu[0][1]); \
        accg[1][0] = MFMA16(x1_, bg0_, accg[1][0]); accg[1][1] = MFMA16(x1_, bg1_, accg[1][1]); \
        accu[1][0] = MFMA16(x1_, bu0_, accu[1][0]); accu[1][1] = MFMA16(x1_, bu1_, accu[1][1]); \
        accg[2][0] = MFMA16(x2_, bg0_, accg[2][0]); accg[2][1] = MFMA16(x2_, bg1_, accg[2][1]); \
        accu[2][0] = MFMA16(x2_, bu0_, accu[2][0]); accu[2][1] = MFMA16(x2_, bu1_, accu[2][1]); \
        accg[3][0] = MFMA16(x3_, bg0_, accg[3][0]); accg[3][1] = MFMA16(x3_, bg1_, accg[3][1]); \
        accu[3][0] = MFMA16(x3_, bu0_, accu[3][0]); accu[3][1] = MFMA16(x3_, bu1_, accu[3][1]); }
// one pipeline iteration: read rb_, write q-set W (=B(t+1)) to wb_, load B(t+2) into q-set L
#define G1_ITER(t_, rb_, wb_, W0,W1,W2,W3, L0,L1,L2,L3) { \
        G1_WRITEQ(W0, W1, W2, W3, wb_); \
        { int t2_ = (t_) + 2; if (t2_ > NT - 1) t2_ = NT - 1; G1_LOADQ(L0, L1, L2, L3, t2_); } \
        { unsigned kf_ = (unsigned)(t_) * 64 + 32; \
          aB0 = *(const bf16x8*)(Ap0 + kf_); aB1 = *(const bf16x8*)(Ap1 + kf_); \
          aB2 = *(const bf16x8*)(Ap2 + kf_); aB3 = *(const bf16x8*)(Ap3 + kf_); } \
        G1_COMPUTE(rb_, 0, aA0, aA1, aA2, aA3); \
        { int t1_ = (t_) + 1; if (t1_ > NT - 1) t1_ = NT - 1; unsigned kf_ = (unsigned)t1_ * 64; \
          aA0 = *(const bf16x8*)(Ap0 + kf_); aA1 = *(const bf16x8*)(Ap1 + kf_); \
          aA2 = *(const bf16x8*)(Ap2 + kf_); aA3 = *(const bf16x8*)(Ap3 + kf_); } \
        G1_COMPUTE(rb_, 1, aB0, aB1, aB2, aB3); \
        BARRIER(); }

    // prologue: buf0 = B(0); qA = B(1); aA = A(0,s0)
    G1_LOADQ(gA0, gA1, uA0, uA1, 0);
    asm volatile("s_waitcnt vmcnt(0)" ::: "memory");
    G1_WRITEQ(gA0, gA1, uA0, uA1, 0);
    G1_LOADQ(gA0, gA1, uA0, uA1, 1);
    aA0 = *(const bf16x8*)(Ap0); aA1 = *(const bf16x8*)(Ap1);
    aA2 = *(const bf16x8*)(Ap2); aA3 = *(const bf16x8*)(Ap3);
    BARRIER();

    for (int t = 0; t < NT; t += 2) {
        G1_ITER(t,     0, 1, gA0, gA1, uA0, uA1, gB0, gB1, uB0, uB1)
        G1_ITER(t + 1, 1, 0, gB0, gB1, uB0, uB1, gA0, gA1, uA0, uA1)
    }

    int hbase = (g < E_NUM) ? rowbase : T_TOK;
#pragma unroll
    for (int i = 0; i < 4; i++) {
#pragma unroll
        for (int jn = 0; jn < 2; jn++) {
#pragma unroll
            for (int r = 0; r < 4; r++) {
                int row = mstart + wave * 64 + i * 16 + h * 4 + r;
                if (row < ng) {
                    float gv = accg[i][jn][r], uv = accu[i][jn][r];
                    float hv = gv / (1.f + expf(-gv)) * uv;  // silu(g)*u
                    int col = nt * 32 + jn * 16 + ln;
                    hmid[(size_t)(hbase + row) * I_DIM + col] = f2bs(hv);
                }
            }
        }
    }
}

// ---------------- GEMM2 merged: out[tok] = hmid_routed . dwn[e] + hmid_shared . sd
// 256 thr = 4 m-waves x 64 rows (BM=256). BN=32. BK=64. Two K-loops share acc; single write.
// grid.x = H/32 (64), grid.y = g*8 + mt
__global__ __launch_bounds__(256, 3) void gemm2_kernel(
    const unsigned short* __restrict__ hmid, const float* __restrict__ dwn,
    const float* __restrict__ sd, const int* __restrict__ perm,
    const int* __restrict__ off, float* __restrict__ out) {
    int nt = blockIdx.x;
    int g = blockIdx.y >> 3;
    int mt = blockIdx.y & 7;
    int rowbase = off[g];
    int ng = off[g + 1] - rowbase;
    int mstart = mt * 256;
    if (mstart >= ng) return;

    __shared__ unsigned short Bs[2][32 * 64];   // 2 x 4 KB

    int tid = threadIdx.x;
    int wave = tid >> 6, lane = tid & 63;
    int ln = lane & 15, h = lane >> 4;

    // A offsets: routed rows (grouped) and shared rows (token order), 4 frags each
    unsigned aR0, aR1, aR2, aR3, aS0, aS1, aS2, aS3;
#define MKA(i, dR, dS) { int r_ = mstart + wave * 64 + i * 16 + ln; \
        r_ = (r_ < ng) ? r_ : (ng - 1); \
        int tok_ = perm[rowbase + r_]; \
        dR = (unsigned)(rowbase + r_) * I_DIM + h * 8; \
        dS = (unsigned)(T_TOK + tok_) * I_DIM + h * 8; }
    MKA(0, aR0, aS0) MKA(1, aR1, aS1) MKA(2, aR2, aS2) MKA(3, aR3, aS3)
#undef MKA

    const float* pbR = dwn + (size_t)g * I_DIM * H_DIM + nt * 32;
    const float* pbS = sd + nt * 32;
    int nb = (tid & 7) * 4;
    int kk = (tid >> 3) * 2;
    const size_t ldb = H_DIM;

    f32x4 zero = {0.f, 0.f, 0.f, 0.f};
    f32x4 acc[4][2];
#pragma unroll
    for (int i = 0; i < 4; i++)
#pragma unroll
        for (int j = 0; j < 2; j++) acc[i][j] = zero;

    const int NT2 = I_DIM / 64;  // 64, even
    f32x4 qA0, qA1, qB0, qB1;
    bf16x8 aA0, aA1, aA2, aA3, aB0, aB1, aB2, aB3;

#define G2_LOADQ(q0_, q1_, bp_, t_) { size_t ko_ = (size_t)(t_) * 64 * ldb + (size_t)kk * ldb + nb; \
        q0_ = *reinterpret_cast<const f32x4*>((bp_) + ko_); \
        q1_ = *reinterpret_cast<const f32x4*>((bp_) + ko_ + ldb); }
#define G2_WRITEQ(q0_, q1_, buf_) { _Pragma("unroll") \
        for (int i_ = 0; i_ < 4; i_++) { int n_ = nb + i_; \
            unsigned o_ = (unsigned)f2bs(q0_[i_]) | ((unsigned)f2bs(q1_[i_]) << 16); \
            int ob_ = (n_ * 128 + kk * 2) ^ BSWZ(n_); \
            *reinterpret_cast<unsigned*>((char*)Bs[buf_] + ob_) = o_; } }
#define G2_COMPUTE(rb_, s_, x0_, x1_, x2_, x3_) { \
        bf16x8 b0_ = bload(Bs[rb_], ln, s_, h), b1_ = bload(Bs[rb_], 16 + ln, s_, h); \
        acc[0][0] = MFMA16(x0_, b0_, acc[0][0]); acc[0][1] = MFMA16(x0_, b1_, acc[0][1]); \
        acc[1][0] = MFMA16(x1_, b0_, acc[1][0]); acc[1][1] = MFMA16(x1_, b1_, acc[1][1]); \
        acc[2][0] = MFMA16(x2_, b0_, acc[2][0]); acc[2][1] = MFMA16(x2_, b1_, acc[2][1]); \
        acc[3][0] = MFMA16(x3_, b0_, acc[3][0]); acc[3][1] = MFMA16(x3_, b1_, acc[3][1]); }
#define G2_ALOAD(x0_, x1_, x2_, x3_, a0_, a1_, a2_, a3_, kf_) { \
        x0_ = *(const bf16x8*)(hmid + a0_ + (kf_)); x1_ = *(const bf16x8*)(hmid + a1_ + (kf_)); \
        x2_ = *(const bf16x8*)(hmid + a2_ + (kf_)); x3_ = *(const bf16x8*)(hmid + a3_ + (kf_)); }
#define G2_ITER(t_, rb_, wb_, W0,W1, L0,L1, bp_, a0_, a1_, a2_, a3_) { \
        G2_WRITEQ(W0, W1, wb_); \
        { int t2_ = (t_) + 2; if (t2_ > NT2 - 1) t2_ = NT2 - 1; G2_LOADQ(L0, L1, bp_, t2_); } \
        G2_ALOAD(aB0, aB1, aB2, aB3, a0_, a1_, a2_, a3_, (unsigned)(t_) * 64 + 32); \
        G2_COMPUTE(rb_, 0, aA0, aA1, aA2, aA3); \
        { int t1_ = (t_) + 1; if (t1_ > NT2 - 1) t1_ = NT2 - 1; \
          G2_ALOAD(aA0, aA1, aA2, aA3, a0_, a1_, a2_, a3_, (unsigned)t1_ * 64); } \
        G2_COMPUTE(rb_, 1, aB0, aB1, aB2, aB3); \
        BARRIER(); }
#define G2_KLOOP(bp_, a0_, a1_, a2_, a3_) { \
        G2_LOADQ(qA0, qA1, bp_, 0); \
        asm volatile("s_waitcnt vmcnt(0)" ::: "memory"); \
        G2_WRITEQ(qA0, qA1, 0); \
        G2_LOADQ(qA0, qA1, bp_, 1); \
        G2_ALOAD(aA0, aA1, aA2, aA3, a0_, a1_, a2_, a3_, 0u); \
        BARRIER(); \
        for (int t = 0; t < NT2; t += 2) { \
            G2_ITER(t,     0, 1, qA0, qA1, qB0, qB1, bp_, a0_, a1_, a2_, a3_) \
            G2_ITER(t + 1, 1, 0, qB0, qB1, qA0, qA1, bp_, a0_, a1_, a2_, a3_) \
        } }

    G2_KLOOP(pbR, aR0, aR1, aR2, aR3)   // routed expert down-proj
    G2_KLOOP(pbS, aS0, aS1, aS2, aS3)   // shared expert down-proj (accumulates)

#pragma unroll
    for (int i = 0; i < 4; i++) {
#pragma unroll
        for (int j = 0; j < 2; j++) {
#pragma unroll
            for (int r = 0; r < 4; r++) {
                int row = mstart + wave * 64 + i * 16 + h * 4 + r;
                if (row < ng) {
                    int tok = perm[rowbase + row];
                    int col = nt * 32 + j * 16 + ln;
                    out[(size_t)tok * H_DIM + col] = acc[i][j][r];
                }
            }
        }
    }
}

extern "C" void kernel_launch(void* const* d_in, const int* in_sizes, int n_in,
                              void* d_out, int out_size, void* d_ws, size_t ws_size,
                              hipStream_t stream) {
    (void)in_sizes; (void)n_in; (void)out_size;
    const float* hs  = (const float*)d_in[0];
    const float* rw  = (const float*)d_in[1];
    const float* gup = (const float*)d_in[2];
    const float* dwn = (const float*)d_in[3];
    const float* sg  = (const float*)d_in[4];
    const float* su  = (const float*)d_in[5];
    const float* sd  = (const float*)d_in[6];
    float* out = (float*)d_out;
    float* out_scores = out + (size_t)T_TOK * H_DIM;

    char* w = (char*)d_ws;
    size_t o = 0;
    auto alloc = [&](size_t bytes) {
        void* p = w + o;
        o += (bytes + 255) & ~(size_t)255;
        return p;
    };
    unsigned short* xb   = (unsigned short*)alloc((size_t)T_TOK * H_DIM * 2);
    unsigned short* xs   = (unsigned short*)alloc((size_t)T_TOK * H_DIM * 2);
    unsigned short* hmid = (unsigned short*)alloc((size_t)2 * T_TOK * I_DIM * 2);
    int* eidx    = (int*)alloc(T_TOK * 4);
    int* perm    = (int*)alloc(T_TOK * 4);
    int* off     = (int*)alloc(64 * 4);
    if (ws_size < o) return;  // insufficient workspace

    router_convert_kernel<<<T_TOK / 4, 256, 0, stream>>>(hs, rw, out_scores, eidx, xb, xs);
    group_kernel<<<1, 256, 0, stream>>>(eidx, perm, off);

    gemm1_kernel<<<dim3(I_DIM / 32, 9 * 8), 256, 0, stream>>>(
        xb, xs, gup, sg, su, perm, off, hmid);
    gemm2_kernel<<<dim3(H_DIM / 32, E_NUM * 8), 256, 0, stream>>>(
        hmid, dwn, sd, perm, off, out);
}

// Round 9
// 507.939 us; speedup vs baseline: 1.6933x; 1.6933x over previous
//
#include <hip/hip_runtime.h>
#include <hip/hip_bf16.h>

#define H_DIM 2048
#define E_NUM 8
#define I_DIM 4096
#define TWO_I 8192
#define T_TOK 2048

#define BM 256
#define BN 64
#define BK 64

typedef __bf16 bf16x8 __attribute__((ext_vector_type(8)));
typedef float f32x4 __attribute__((ext_vector_type(4)));

static __device__ __forceinline__ unsigned short f2bs(float x) {
    __hip_bfloat16 h = __float2bfloat16(x);
    return __builtin_bit_cast(unsigned short, h);
}

#define GLL(gsrc, ldst) __builtin_amdgcn_global_load_lds( \
    (const __attribute__((address_space(1))) void*)(gsrc), \
    (__attribute__((address_space(3))) void*)(ldst), 16, 0, 0)

#define MFMA16(a, b, c) __builtin_amdgcn_mfma_f32_16x16x32_bf16(a, b, c, 0, 0, 0)
#define BSWZ(n) (((((n) & 7) ^ (((n) >> 2) & 7))) << 4)
#define A_SRC_CHUNK(lane) ((((lane) & 7) ^ (((lane) >> 3) & 7)) * 8)
// barrier WITHOUT vmcnt drain: LDS writes visible; global/GLL loads stay in flight
#define BARRIER() asm volatile("s_waitcnt lgkmcnt(0)\ns_barrier" ::: "memory")

static __device__ __forceinline__ bf16x8 bload(
    const unsigned short* __restrict__ Bs, int n, int s, int h) {
    int off = (n * 128 + s * 64 + h * 16) ^ BSWZ(n);
    return *reinterpret_cast<const bf16x8*>((const char*)Bs + off);
}

static __device__ __forceinline__ bf16x8 aload(
    const unsigned short* __restrict__ As, int row, int s, int h) {
    int off = row * 128 + ((s * 64 + h * 16) ^ ((row & 7) << 4));
    return *reinterpret_cast<const bf16x8*>((const char*)As + off);
}

// ---------------- fused router + convert: one wave per token ----------------
__global__ __launch_bounds__(256) void router_convert_kernel(
    const float* __restrict__ hs, const float* __restrict__ rw,
    float* __restrict__ out_scores, int* __restrict__ eidx,
    unsigned short* __restrict__ xb, unsigned short* __restrict__ xs) {
    int tok = blockIdx.x * 4 + (threadIdx.x >> 6);
    int lane = threadIdx.x & 63;
    const float* row = hs + (size_t)tok * H_DIM;
    float4 v[8];
    float acc[E_NUM];
#pragma unroll
    for (int e = 0; e < E_NUM; e++) acc[e] = 0.f;
#pragma unroll
    for (int i = 0; i < 8; i++) {
        int hb = i * 256 + lane * 4;
        v[i] = *reinterpret_cast<const float4*>(row + hb);
        const float* w0 = rw + (size_t)hb * E_NUM;
#pragma unroll
        for (int e = 0; e < E_NUM; e++) {
            acc[e] += v[i].x * w0[e] + v[i].y * w0[E_NUM + e] +
                      v[i].z * w0[2 * E_NUM + e] + v[i].w * w0[3 * E_NUM + e];
        }
    }
#pragma unroll
    for (int e = 0; e < E_NUM; e++) {
#pragma unroll
        for (int o = 32; o > 0; o >>= 1) acc[e] += __shfl_xor(acc[e], o, 64);
    }
    int best = 0; float bv = acc[0];
#pragma unroll
    for (int e = 1; e < E_NUM; e++) { if (acc[e] > bv) { bv = acc[e]; best = e; } }
    float sc = 1.f / (1.f + expf(-bv));
    if (lane < E_NUM) out_scores[(size_t)lane * T_TOK + tok] = (lane == best) ? sc : 0.f;
    if (lane == 0) eidx[tok] = best;
    unsigned short* xbr = xb + (size_t)tok * H_DIM;
    unsigned short* xsr = xs + (size_t)tok * H_DIM;
#pragma unroll
    for (int i = 0; i < 8; i++) {
        int hb = i * 256 + lane * 4;
        ushort4 b, s4;
        b.x = f2bs(v[i].x); b.y = f2bs(v[i].y); b.z = f2bs(v[i].z); b.w = f2bs(v[i].w);
        s4.x = f2bs(v[i].x * sc); s4.y = f2bs(v[i].y * sc);
        s4.z = f2bs(v[i].z * sc); s4.w = f2bs(v[i].w * sc);
        *reinterpret_cast<ushort4*>(xbr + hb) = b;
        *reinterpret_cast<ushort4*>(xsr + hb) = s4;
    }
}

// ---------------- grouping ----------------
__global__ void group_kernel(const int* __restrict__ eidx, int* __restrict__ perm,
                             int* __restrict__ off) {
    __shared__ int cnt[E_NUM];
    __shared__ int base[E_NUM];
    int t = threadIdx.x;
    if (t < E_NUM) cnt[t] = 0;
    __syncthreads();
    for (int i = t; i < T_TOK; i += 256) atomicAdd(&cnt[eidx[i]], 1);
    __syncthreads();
    if (t == 0) {
        int s = 0;
        for (int e = 0; e < E_NUM; e++) { base[e] = s; off[e] = s; s += cnt[e]; }
        off[E_NUM] = s;
    }
    __syncthreads();
    for (int i = t; i < T_TOK; i += 256) {
        int e = eidx[i];
        int p = atomicAdd(&base[e], 1);
        perm[p] = i;
    }
}

// ---------------- GEMM1: R3 structure + counted-wait pipeline ----------------
// 256 thr, BM=256, BN=64 gate + 64 up, BK=64. As dbuf (GLL), B single-buf reg-staged.
// grid.x = I/64, grid.y = g*8 + mt
__global__ __launch_bounds__(256, 2) void gemm1_kernel(
    const unsigned short* __restrict__ xb, const unsigned short* __restrict__ xs,
    const float* __restrict__ gup, const float* __restrict__ sg,
    const float* __restrict__ su, const int* __restrict__ perm,
    const int* __restrict__ off, unsigned short* __restrict__ hmid) {
    int nt = blockIdx.x;
    int g = blockIdx.y >> 3;
    int mt = blockIdx.y & 7;
    int rowbase, ng;
    if (g < E_NUM) { rowbase = off[g]; ng = off[g + 1] - rowbase; }
    else { rowbase = 0; ng = T_TOK; }
    int mstart = mt * BM;
    if (mstart >= ng) return;

    __shared__ unsigned short As[2][BM * BK];  // 2 x 32 KB
    __shared__ unsigned short Bg[BN * BK];     // 8 KB
    __shared__ unsigned short Bu[BN * BK];     // 8 KB

    int tid = threadIdx.x;
    int wave = tid >> 6, lane = tid & 63;
    int h = lane >> 4, ln = lane & 15;

    const unsigned short* Abase = (g == E_NUM) ? xb : xs;
    unsigned int aoff[8];
#pragma unroll
    for (int j = 0; j < 8; j++) {
        int r = wave * 64 + j * 8 + (lane >> 3);
        int sr = mstart + r; sr = (sr < ng) ? sr : (ng - 1);
        int tokr = (g < E_NUM) ? perm[rowbase + sr] : sr;
        aoff[j] = (unsigned int)tokr * H_DIM + A_SRC_CHUNK(lane);
    }
    int n0 = nt * BN;
    const float* gbase;
    const float* ubase;
    size_t ldb;
    if (g < E_NUM) {
        gbase = gup + (size_t)g * H_DIM * TWO_I + n0;
        ubase = gbase + I_DIM;
        ldb = TWO_I;
    } else {
        gbase = sg + n0;
        ubase = su + n0;
        ldb = I_DIM;
    }
    int k0i = wave * 16 + ((lane >> 4) << 2);  // 4 k-rows per lane
    int nb = (lane & 15) << 2;                 // 4 n-cols per lane
    const float* pg = gbase + (size_t)k0i * ldb + nb;
    const float* pu = ubase + (size_t)k0i * ldb + nb;

    f32x4 zero = {0.f, 0.f, 0.f, 0.f};
    f32x4 accg[4][4], accu[4][4];
#pragma unroll
    for (int i = 0; i < 4; i++)
#pragma unroll
        for (int j = 0; j < 4; j++) { accg[i][j] = zero; accu[i][j] = zero; }

    const int NT = H_DIM / BK;   // 32
    f32x4 qg0, qg1, qg2, qg3, qu0, qu1, qu2, qu3;

#define G1_QLOAD(t_) { size_t ko_ = (size_t)(t_) * BK * ldb; \
        const float* p_ = pg + ko_; \
        qg0 = *reinterpret_cast<const f32x4*>(p_); \
        qg1 = *reinterpret_cast<const f32x4*>(p_ + ldb); \
        qg2 = *reinterpret_cast<const f32x4*>(p_ + 2 * ldb); \
        qg3 = *reinterpret_cast<const f32x4*>(p_ + 3 * ldb); \
        p_ = pu + ko_; \
        qu0 = *reinterpret_cast<const f32x4*>(p_); \
        qu1 = *reinterpret_cast<const f32x4*>(p_ + ldb); \
        qu2 = *reinterpret_cast<const f32x4*>(p_ + 2 * ldb); \
        qu3 = *reinterpret_cast<const f32x4*>(p_ + 3 * ldb); }
#define G1_BWRITE() { _Pragma("unroll") \
        for (int i_ = 0; i_ < 4; i_++) { int n_ = nb + i_; \
            ushort4 og_, ou_; \
            og_.x = f2bs(qg0[i_]); og_.y = f2bs(qg1[i_]); \
            og_.z = f2bs(qg2[i_]); og_.w = f2bs(qg3[i_]); \
            ou_.x = f2bs(qu0[i_]); ou_.y = f2bs(qu1[i_]); \
            ou_.z = f2bs(qu2[i_]); ou_.w = f2bs(qu3[i_]); \
            int ob_ = (n_ * 128 + k0i * 2) ^ BSWZ(n_); \
            *reinterpret_cast<ushort4*>((char*)Bg + ob_) = og_; \
            *reinterpret_cast<ushort4*>((char*)Bu + ob_) = ou_; } }
#define G1_AGLL(t_, buf_) { _Pragma("unroll") \
        for (int j_ = 0; j_ < 8; j_++) \
            GLL(Abase + aoff[j_] + (unsigned)(t_) * BK, \
                &As[buf_][(wave * 64 + j_ * 8) * BK]); }

    // prologue: B(0)->LDS, A(0)->As[0], A(1)->As[1], B(1)->regs
    G1_QLOAD(0);
    G1_AGLL(0, 0);
    asm volatile("s_waitcnt vmcnt(0)" ::: "memory");
    G1_BWRITE();
    G1_AGLL(1, 1);
    G1_QLOAD(1);
    BARRIER();

    for (int t = 0; t < NT; ++t) {
        const unsigned short* Ab = &As[t & 1][0];
#pragma unroll
        for (int s = 0; s < 2; s++) {
            bf16x8 a0 = aload(Ab, wave * 64 + 0 * 16 + ln, s, h);
            bf16x8 a1 = aload(Ab, wave * 64 + 1 * 16 + ln, s, h);
            bf16x8 a2 = aload(Ab, wave * 64 + 2 * 16 + ln, s, h);
            bf16x8 a3 = aload(Ab, wave * 64 + 3 * 16 + ln, s, h);
#pragma unroll
            for (int j = 0; j < 4; j++) {
                bf16x8 bg = bload(Bg, j * 16 + ln, s, h);
                accg[0][j] = MFMA16(a0, bg, accg[0][j]);
                accg[1][j] = MFMA16(a1, bg, accg[1][j]);
                accg[2][j] = MFMA16(a2, bg, accg[2][j]);
                accg[3][j] = MFMA16(a3, bg, accg[3][j]);
            }
#pragma unroll
            for (int j = 0; j < 4; j++) {
                bf16x8 bu = bload(Bu, j * 16 + ln, s, h);
                accu[0][j] = MFMA16(a0, bu, accu[0][j]);
                accu[1][j] = MFMA16(a1, bu, accu[1][j]);
                accu[2][j] = MFMA16(a2, bu, accu[2][j]);
                accu[3][j] = MFMA16(a3, bu, accu[3][j]);
            }
        }
        BARRIER();                       // reads of As[t&1], B(t) done
        if (t + 1 < NT) {
            G1_BWRITE();                 // B(t+1); implicit counted vmcnt here only
            int tc = t + 2; if (tc > NT - 1) tc = NT - 1;
            G1_AGLL(tc, t & 1);          // A(t+2) into the buffer just read
            G1_QLOAD(tc);                // B(t+2) -> regs, stays in flight
            BARRIER();                   // B(t+1) visible; loads NOT drained
        }
    }

    int hbase = (g < E_NUM) ? rowbase : T_TOK;
#pragma unroll
    for (int i = 0; i < 4; i++) {
#pragma unroll
        for (int j = 0; j < 4; j++) {
#pragma unroll
            for (int r = 0; r < 4; r++) {
                int row = wave * 64 + i * 16 + h * 4 + r;
                int sr = mstart + row;
                if (sr < ng) {
                    float gv = accg[i][j][r], uv = accu[i][j][r];
                    float hv = gv / (1.f + expf(-gv)) * uv;  // silu(g)*u
                    int col = n0 + j * 16 + ln;
                    hmid[(size_t)(hbase + sr) * I_DIM + col] = f2bs(hv);
                }
            }
        }
    }
}

// ---------------- GEMM2: down proj, same pipeline. ADD=0 shared writes, ADD=1 routed +=
// 256 thr, BM=256, BN=64, BK=64. grid.x = H/64. ADD=0: grid.y=mt(0..7); ADD=1: g*8+mt
template <int ADD>
__global__ __launch_bounds__(256, 2) void gemm2_kernel(
    const unsigned short* __restrict__ hmid, const float* __restrict__ dwn,
    const float* __restrict__ sd, const int* __restrict__ perm,
    const int* __restrict__ off, float* __restrict__ out) {
    int nt = blockIdx.x;
    int g, mt, rowbase, ng, hbase;
    if (ADD) {
        g = blockIdx.y >> 3; mt = blockIdx.y & 7;
        rowbase = off[g]; ng = off[g + 1] - rowbase; hbase = rowbase;
    } else {
        g = E_NUM; mt = blockIdx.y; rowbase = 0; ng = T_TOK; hbase = T_TOK;
    }
    int mstart = mt * BM;
    if (mstart >= ng) return;

    __shared__ unsigned short As[2][BM * BK];  // 2 x 32 KB
    __shared__ unsigned short Bs[BN * BK];     // 8 KB

    int tid = threadIdx.x;
    int wave = tid >> 6, lane = tid & 63;
    int h = lane >> 4, ln = lane & 15;

    unsigned int aoff[8];
#pragma unroll
    for (int j = 0; j < 8; j++) {
        int r = wave * 64 + j * 8 + (lane >> 3);
        int sr = mstart + r; sr = (sr < ng) ? sr : (ng - 1);
        aoff[j] = (unsigned int)(hbase + sr) * I_DIM + A_SRC_CHUNK(lane);
    }
    int n0 = nt * BN;
    const float* bbase = ADD ? (dwn + (size_t)g * I_DIM * H_DIM + n0) : (sd + n0);
    const size_t ldb = H_DIM;
    int k0i = wave * 16 + ((lane >> 4) << 2);
    int nb = (lane & 15) << 2;
    const float* pb = bbase + (size_t)k0i * ldb + nb;

    f32x4 zero = {0.f, 0.f, 0.f, 0.f};
    f32x4 acc[4][4];
#pragma unroll
    for (int i = 0; i < 4; i++)
#pragma unroll
        for (int j = 0; j < 4; j++) acc[i][j] = zero;

    const int NT2 = I_DIM / BK;  // 64
    f32x4 qb0, qb1, qb2, qb3;

#define G2_QLOAD(t_) { size_t ko_ = (size_t)(t_) * BK * ldb; \
        const float* p_ = pb + ko_; \
        qb0 = *reinterpret_cast<const f32x4*>(p_); \
        qb1 = *reinterpret_cast<const f32x4*>(p_ + ldb); \
        qb2 = *reinterpret_cast<const f32x4*>(p_ + 2 * ldb); \
        qb3 = *reinterpret_cast<const f32x4*>(p_ + 3 * ldb); }
#define G2_BWRITE() { _Pragma("unroll") \
        for (int i_ = 0; i_ < 4; i_++) { int n_ = nb + i_; \
            ushort4 o_; \
            o_.x = f2bs(qb0[i_]); o_.y = f2bs(qb1[i_]); \
            o_.z = f2bs(qb2[i_]); o_.w = f2bs(qb3[i_]); \
            int ob_ = (n_ * 128 + k0i * 2) ^ BSWZ(n_); \
            *reinterpret_cast<ushort4*>((char*)Bs + ob_) = o_; } }
#define G2_AGLL(t_, buf_) { _Pragma("unroll") \
        for (int j_ = 0; j_ < 8; j_++) \
            GLL(hmid + aoff[j_] + (unsigned)(t_) * BK, \
                &As[buf_][(wave * 64 + j_ * 8) * BK]); }

    G2_QLOAD(0);
    G2_AGLL(0, 0);
    asm volatile("s_waitcnt vmcnt(0)" ::: "memory");
    G2_BWRITE();
    G2_AGLL(1, 1);
    G2_QLOAD(1);
    BARRIER();

    for (int t = 0; t < NT2; ++t) {
        const unsigned short* Ab = &As[t & 1][0];
#pragma unroll
        for (int s = 0; s < 2; s++) {
            bf16x8 a0 = aload(Ab, wave * 64 + 0 * 16 + ln, s, h);
            bf16x8 a1 = aload(Ab, wave * 64 + 1 * 16 + ln, s, h);
            bf16x8 a2 = aload(Ab, wave * 64 + 2 * 16 + ln, s, h);
            bf16x8 a3 = aload(Ab, wave * 64 + 3 * 16 + ln, s, h);
#pragma unroll
            for (int j = 0; j < 4; j++) {
                bf16x8 b = bload(Bs, j * 16 + ln, s, h);
                acc[0][j] = MFMA16(a0, b, acc[0][j]);
                acc[1][j] = MFMA16(a1, b, acc[1][j]);
                acc[2][j] = MFMA16(a2, b, acc[2][j]);
                acc[3][j] = MFMA16(a3, b, acc[3][j]);
            }
        }
        BARRIER();
        if (t + 1 < NT2) {
            G2_BWRITE();
            int tc = t + 2; if (tc > NT2 - 1) tc = NT2 - 1;
            G2_AGLL(tc, t & 1);
            G2_QLOAD(tc);
            BARRIER();
        }
    }

#pragma unroll
    for (int i = 0; i < 4; i++) {
#pragma unroll
        for (int j = 0; j < 4; j++) {
#pragma unroll
            for (int r = 0; r < 4; r++) {
                int row = wave * 64 + i * 16 + h * 4 + r;
                int sr = mstart + row;
                if (sr < ng) {
                    int tok = ADD ? perm[rowbase + sr] : sr;
                    int col = n0 + j * 16 + ln;
                    float v = acc[i][j][r];
                    float* o = out + (size_t)tok * H_DIM + col;
                    if (ADD) *o += v; else *o = v;
                }
            }
        }
    }
}

extern "C" void kernel_launch(void* const* d_in, const int* in_sizes, int n_in,
                              void* d_out, int out_size, void* d_ws, size_t ws_size,
                              hipStream_t stream) {
    (void)in_sizes; (void)n_in; (void)out_size;
    const float* hs  = (const float*)d_in[0];
    const float* rw  = (const float*)d_in[1];
    const float* gup = (const float*)d_in[2];
    const float* dwn = (const float*)d_in[3];
    const float* sg  = (const float*)d_in[4];
    const float* su  = (const float*)d_in[5];
    const float* sd  = (const float*)d_in[6];
    float* out = (float*)d_out;
    float* out_scores = out + (size_t)T_TOK * H_DIM;

    char* w = (char*)d_ws;
    size_t o = 0;
    auto alloc = [&](size_t bytes) {
        void* p = w + o;
        o += (bytes + 255) & ~(size_t)255;
        return p;
    };
    unsigned short* xb   = (unsigned short*)alloc((size_t)T_TOK * H_DIM * 2);
    unsigned short* xs   = (unsigned short*)alloc((size_t)T_TOK * H_DIM * 2);
    unsigned short* hmid = (unsigned short*)alloc((size_t)2 * T_TOK * I_DIM * 2);
    int* eidx    = (int*)alloc(T_TOK * 4);
    int* perm    = (int*)alloc(T_TOK * 4);
    int* off     = (int*)alloc(64 * 4);
    if (ws_size < o) return;  // insufficient workspace

    router_convert_kernel<<<T_TOK / 4, 256, 0, stream>>>(hs, rw, out_scores, eidx, xb, xs);
    group_kernel<<<1, 256, 0, stream>>>(eidx, perm, off);

    gemm1_kernel<<<dim3(I_DIM / BN, 9 * 8), 256, 0, stream>>>(
        xb, xs, gup, sg, su, perm, off, hmid);
    gemm2_kernel<0><<<dim3(H_DIM / BN, 8), 256, 0, stream>>>(hmid, dwn, sd, perm, off, out);
    gemm2_kernel<1><<<dim3(H_DIM / BN, E_NUM * 8), 256, 0, stream>>>(hmid, dwn, sd, perm, off, out);
}